// Round 1
// baseline (1196.981 us; speedup 1.0000x reference)
//
#include <hip/hip_runtime.h>
#include <hip/hip_bf16.h>

// LinearLayer_PSLoRA: out = X @ W^T + bias + 0.5 * (X @ A[lab]) @ B_lora^T
// B=8, S=2048, D_IN=4096, D_OUT=4096, R=32, 5 labelers. All inputs fp32.
// Strategy: cast to bf16, fold LoRA into one extra K-step of the main MFMA GEMM:
//   out = [Xb | axb] @ [Wb | Bb]^T + bias,  axb = 0.5 * Xb @ A[lab]  (K = 4096+32)

typedef __bf16 bf16_t;
typedef bf16_t bf16x4 __attribute__((ext_vector_type(4)));
typedef bf16_t bf16x8 __attribute__((ext_vector_type(8)));
typedef float f32x4 __attribute__((ext_vector_type(4)));

#define S_    2048
#define DIN   4096
#define DOUT  4096
#define R_    32
#define M_TOT 16384

__device__ __forceinline__ void async_cp16(const bf16_t* g, bf16_t* l) {
  // global -> LDS direct DMA, 16B/lane. LDS dest must be wave-uniform base; HW
  // scatters lane i to base + i*16.
  __builtin_amdgcn_global_load_lds((const __attribute__((address_space(1))) void*)g,
                                   (__attribute__((address_space(3))) void*)l,
                                   16, 0, 0);
}

// ---------------------------------------------------------------- casts -----
__global__ void cast_f32_to_bf16(const float* __restrict__ src,
                                 bf16_t* __restrict__ dst, int n4) {
  int i = blockIdx.x * blockDim.x + threadIdx.x;
  if (i >= n4) return;
  f32x4 v = ((const f32x4*)src)[i];
  bf16x4 o = { (bf16_t)v[0], (bf16_t)v[1], (bf16_t)v[2], (bf16_t)v[3] };
  ((bf16x4*)dst)[i] = o;
}

// lora_A [5][DIN][R] fp32 -> At [5][R][DIN] bf16 (K-contiguous rows for MFMA B-op)
__global__ void transpose_loraA(const float* __restrict__ A,
                                bf16_t* __restrict__ At) {
  int idx = blockIdx.x * blockDim.x + threadIdx.x;
  if (idx >= 5 * R_ * DIN) return;
  int l = idx / (R_ * DIN);
  int rem = idx % (R_ * DIN);
  int r = rem / DIN;
  int k = rem % DIN;
  At[idx] = (bf16_t)A[(size_t)l * DIN * R_ + (size_t)k * R_ + r];
}

// ------------------------------------------------- axb = 0.5 * Xb @ A[lab] --
// Tile: BM=128, BN=32, BK=64. 4 waves, each 32 rows x 32 cols (2x2 MFMA tiles).
__global__ __launch_bounds__(256) void ax_gemm(
    const bf16_t* __restrict__ Xb, const bf16_t* __restrict__ At,
    const int* __restrict__ lab_idx, bf16_t* __restrict__ axb) {
  __shared__ bf16_t As[128 * 64];
  __shared__ bf16_t Bs[32 * 64];
  const int tid = threadIdx.x, lane = tid & 63, wv = tid >> 6;
  const int m0 = blockIdx.x * 128;
  const int lab = lab_idx[m0 / S_];
  const bf16_t* Bsrc = At + (size_t)lab * R_ * DIN;

  f32x4 acc[2][2];
#pragma unroll
  for (int i = 0; i < 2; ++i)
#pragma unroll
    for (int j = 0; j < 2; ++j) acc[i][j] = (f32x4){0.f, 0.f, 0.f, 0.f};

  for (int kt = 0; kt < DIN / 64; ++kt) {
    const int k0 = kt * 64;
    __syncthreads();
    {
      const int kk = (lane & 7) * 8;
#pragma unroll
      for (int j = 0; j < 4; ++j) {
        int row = j * 32 + wv * 8 + (lane >> 3);
        async_cp16(Xb + (size_t)(m0 + row) * DIN + k0 + kk,
                   As + j * 2048 + wv * 512);
      }
      int row = wv * 8 + (lane >> 3);
      async_cp16(Bsrc + (size_t)row * DIN + k0 + kk, Bs + wv * 512);
    }
    __syncthreads();
#pragma unroll
    for (int ks = 0; ks < 2; ++ks) {
      bf16x8 a[2], b[2];
#pragma unroll
      for (int mt = 0; mt < 2; ++mt)
        a[mt] = *(const bf16x8*)&As[(wv * 32 + mt * 16 + (lane & 15)) * 64 +
                                    ks * 32 + (lane >> 4) * 8];
#pragma unroll
      for (int nt = 0; nt < 2; ++nt)
        b[nt] = *(const bf16x8*)&Bs[(nt * 16 + (lane & 15)) * 64 +
                                    ks * 32 + (lane >> 4) * 8];
#pragma unroll
      for (int mt = 0; mt < 2; ++mt)
#pragma unroll
        for (int nt = 0; nt < 2; ++nt)
          acc[mt][nt] = __builtin_amdgcn_mfma_f32_16x16x32_bf16(
              a[mt], b[nt], acc[mt][nt], 0, 0, 0);
    }
  }
  // C/D layout: col = lane&15, row = (lane>>4)*4 + reg
#pragma unroll
  for (int mt = 0; mt < 2; ++mt)
#pragma unroll
    for (int nt = 0; nt < 2; ++nt)
#pragma unroll
      for (int r = 0; r < 4; ++r) {
        int m = m0 + wv * 32 + mt * 16 + (lane >> 4) * 4 + r;
        int n = nt * 16 + (lane & 15);
        axb[(size_t)m * R_ + n] = (bf16_t)(0.5f * acc[mt][nt][r]);
      }
}

// ------------------------------------- out = [Xb|axb] @ [Wb|Bb]^T + bias ----
// m97-ladder structure: 128x128 tile, BK=32, 4 waves (2x2), each 64x64
// (4x4 MFMA 16x16x32 tiles). K-loop has 128 Xb/Wb steps + 1 LoRA step.
__global__ __launch_bounds__(256) void main_gemm(
    const bf16_t* __restrict__ Xb, const bf16_t* __restrict__ Wb,
    const bf16_t* __restrict__ axb, const bf16_t* __restrict__ Bb,
    const float* __restrict__ bias, float* __restrict__ out) {
  __shared__ bf16_t As[128 * 32];
  __shared__ bf16_t Bs[128 * 32];
  const int tid = threadIdx.x, lane = tid & 63, wv = tid >> 6;
  const int wr = wv & 1, wc = wv >> 1;
  const int m0 = blockIdx.y * 128, n0 = blockIdx.x * 128;

  f32x4 acc[4][4];
#pragma unroll
  for (int i = 0; i < 4; ++i)
#pragma unroll
    for (int j = 0; j < 4; ++j) acc[i][j] = (f32x4){0.f, 0.f, 0.f, 0.f};

  for (int kt = 0; kt <= 128; ++kt) {
    __syncthreads();
    const bf16_t* aS;
    const bf16_t* bS;
    int lda, k0;
    if (kt < 128) {  // main K: X rows (ld 4096), W rows (ld 4096)
      aS = Xb; bS = Wb; lda = DIN; k0 = kt * 32;
    } else {         // LoRA K-step: axb rows (ld 32), lora_B rows (ld 32)
      aS = axb; bS = Bb; lda = R_; k0 = 0;
    }
    const int kk = (lane & 3) * 8;
#pragma unroll
    for (int j = 0; j < 2; ++j) {
      int row = j * 64 + wv * 16 + (lane >> 2);
      async_cp16(aS + (size_t)(m0 + row) * lda + k0 + kk,
                 As + j * 2048 + wv * 512);
      async_cp16(bS + (size_t)(n0 + row) * lda + k0 + kk,
                 Bs + j * 2048 + wv * 512);
    }
    __syncthreads();
    bf16x8 a[4], b[4];
#pragma unroll
    for (int t = 0; t < 4; ++t) {
      a[t] = *(const bf16x8*)&As[(wr * 64 + t * 16 + (lane & 15)) * 32 +
                                 (lane >> 4) * 8];
      b[t] = *(const bf16x8*)&Bs[(wc * 64 + t * 16 + (lane & 15)) * 32 +
                                 (lane >> 4) * 8];
    }
#pragma unroll
    for (int mt = 0; mt < 4; ++mt)
#pragma unroll
      for (int nt = 0; nt < 4; ++nt)
        acc[mt][nt] = __builtin_amdgcn_mfma_f32_16x16x32_bf16(
            a[mt], b[nt], acc[mt][nt], 0, 0, 0);
  }
  // epilogue: +bias, fp32 store. C/D: col=lane&15, row=(lane>>4)*4+reg
#pragma unroll
  for (int nt = 0; nt < 4; ++nt) {
    int n = n0 + wc * 64 + nt * 16 + (lane & 15);
    float bv = bias[n];
#pragma unroll
    for (int mt = 0; mt < 4; ++mt) {
      int m = m0 + wr * 64 + mt * 16 + (lane >> 4) * 4;
#pragma unroll
      for (int r = 0; r < 4; ++r)
        out[(size_t)(m + r) * DOUT + n] = acc[mt][nt][r] + bv;
    }
  }
}

// ---------------------------------------------------------------------------
extern "C" void kernel_launch(void* const* d_in, const int* in_sizes, int n_in,
                              void* d_out, int out_size, void* d_ws, size_t ws_size,
                              hipStream_t stream) {
  const float* X      = (const float*)d_in[0];  // [8,2048,4096]
  const float* W      = (const float*)d_in[1];  // [4096,4096]
  const float* bias   = (const float*)d_in[2];  // [4096]
  const float* lora_A = (const float*)d_in[3];  // [5,4096,32]
  const float* lora_B = (const float*)d_in[4];  // [4096,32]
  const int*   lab    = (const int*)d_in[5];    // [8]
  float* out = (float*)d_out;

  // workspace layout (bytes): Xb 134217728 | Wb 33554432 | At 1310720 |
  //                           Bb 262144 | axb 1048576   (total ~170.4 MB)
  char* ws = (char*)d_ws;
  bf16_t* Xb  = (bf16_t*)(ws);
  bf16_t* Wb  = (bf16_t*)(ws + 134217728UL);
  bf16_t* At  = (bf16_t*)(ws + 134217728UL + 33554432UL);
  bf16_t* Bb  = (bf16_t*)(ws + 134217728UL + 33554432UL + 1310720UL);
  bf16_t* axb = (bf16_t*)(ws + 134217728UL + 33554432UL + 1310720UL + 262144UL);

  cast_f32_to_bf16<<<65536, 256, 0, stream>>>(X, Xb, (M_TOT * DIN) / 4);
  cast_f32_to_bf16<<<16384, 256, 0, stream>>>(W, Wb, (DOUT * DIN) / 4);
  cast_f32_to_bf16<<<128, 256, 0, stream>>>(lora_B, Bb, (DOUT * R_) / 4);
  transpose_loraA<<<2560, 256, 0, stream>>>(lora_A, At);
  ax_gemm<<<M_TOT / 128, 256, 0, stream>>>(Xb, At, lab, axb);
  dim3 grid(DOUT / 128, M_TOT / 128);
  main_gemm<<<grid, 256, 0, stream>>>(Xb, Wb, axb, Bb, bias, out);
}

// Round 2
// 1127.833 us; speedup vs baseline: 1.0613x; 1.0613x over previous
//
#include <hip/hip_runtime.h>
#include <hip/hip_bf16.h>

// LinearLayer_PSLoRA: out = X @ W^T + bias + 0.5 * (X @ A[lab]) @ B_lora^T
// B=8, S=2048, D_IN=4096, D_OUT=4096, R=32, 5 labelers. All inputs fp32.
// bf16 MFMA; LoRA folded as one peeled K-step: out = [Xb|axb] @ [Wb|Bb]^T + bias.
// R2: split-K ax (1024 blocks), coalesced lora_A transpose, branch-free
//     main_gemm K-loop with pointer-increment staging.

typedef __bf16 bf16_t;
typedef bf16_t bf16x4 __attribute__((ext_vector_type(4)));
typedef bf16_t bf16x8 __attribute__((ext_vector_type(8)));
typedef float f32x4 __attribute__((ext_vector_type(4)));

#define S_    2048
#define DIN   4096
#define DOUT  4096
#define R_    32
#define M_TOT 16384
#define KSPLIT 8

__device__ __forceinline__ void async_cp16(const bf16_t* g, bf16_t* l) {
  // global -> LDS direct DMA, 16B/lane; HW scatters lane i to base + i*16.
  __builtin_amdgcn_global_load_lds((const __attribute__((address_space(1))) void*)g,
                                   (__attribute__((address_space(3))) void*)l,
                                   16, 0, 0);
}

// ---------------------------------------------------------------- casts -----
__global__ void cast_f32_to_bf16(const float* __restrict__ src,
                                 bf16_t* __restrict__ dst, int n4) {
  int i = blockIdx.x * blockDim.x + threadIdx.x;
  if (i >= n4) return;
  f32x4 v = ((const f32x4*)src)[i];
  bf16x4 o = { (bf16_t)v[0], (bf16_t)v[1], (bf16_t)v[2], (bf16_t)v[3] };
  ((bf16x4*)dst)[i] = o;
}

// lora_A [5][DIN][R] fp32 -> At [5][R][DIN] bf16, coalesced via LDS tile.
// Block: one labeler l, one 64-wide K chunk, all 32 r. Grid: 5 * (DIN/64).
__global__ __launch_bounds__(256) void transpose_loraA(
    const float* __restrict__ A, bf16_t* __restrict__ At) {
  __shared__ float tile[64][33];
  const int l = blockIdx.x / (DIN / 64);
  const int k0 = (blockIdx.x % (DIN / 64)) * 64;
  const int tid = threadIdx.x;
  // read: 8 k-rows per pass (32 r contiguous), 8 passes
  {
    const int r = tid & 31, kb = tid >> 5;  // kb 0..7
#pragma unroll
    for (int p = 0; p < 8; ++p) {
      int k = p * 8 + kb;
      tile[k][r] = A[(size_t)l * DIN * R_ + (size_t)(k0 + k) * R_ + r];
    }
  }
  __syncthreads();
  // write: 64 k contiguous per r-row
  {
    const int k = tid & 63, rb = tid >> 6;  // rb 0..3
#pragma unroll
    for (int p = 0; p < 8; ++p) {
      int r = p * 4 + rb;
      At[(size_t)l * R_ * DIN + (size_t)r * DIN + k0 + k] = (bf16_t)tile[k][r];
    }
  }
}

// ------------------------- axp[ks] = Xb[:, ks*512:+512] @ A[lab][ks-chunk] --
// Tile: BM=128, BN=32, BK=64, K-range 512 per block. Grid (M/128, KSPLIT).
__global__ __launch_bounds__(256) void ax_partial(
    const bf16_t* __restrict__ Xb, const bf16_t* __restrict__ At,
    const int* __restrict__ lab_idx, float* __restrict__ axp) {
  __shared__ bf16_t As[128 * 64];
  __shared__ bf16_t Bs[32 * 64];
  const int tid = threadIdx.x, lane = tid & 63, wv = tid >> 6;
  const int m0 = blockIdx.x * 128;
  const int kbase = blockIdx.y * (DIN / KSPLIT);
  const int lab = lab_idx[m0 / S_];
  const bf16_t* Bsrc = At + (size_t)lab * R_ * DIN;

  f32x4 acc[2][2];
#pragma unroll
  for (int i = 0; i < 2; ++i)
#pragma unroll
    for (int j = 0; j < 2; ++j) acc[i][j] = (f32x4){0.f, 0.f, 0.f, 0.f};

  for (int kt = 0; kt < (DIN / KSPLIT) / 64; ++kt) {
    const int k0 = kbase + kt * 64;
    __syncthreads();
    {
      const int kk = (lane & 7) * 8;
#pragma unroll
      for (int j = 0; j < 4; ++j) {
        int row = j * 32 + wv * 8 + (lane >> 3);
        async_cp16(Xb + (size_t)(m0 + row) * DIN + k0 + kk,
                   As + j * 2048 + wv * 512);
      }
      int row = wv * 8 + (lane >> 3);
      async_cp16(Bsrc + (size_t)row * DIN + k0 + kk, Bs + wv * 512);
    }
    __syncthreads();
#pragma unroll
    for (int ks = 0; ks < 2; ++ks) {
      bf16x8 a[2], b[2];
#pragma unroll
      for (int mt = 0; mt < 2; ++mt)
        a[mt] = *(const bf16x8*)&As[(wv * 32 + mt * 16 + (lane & 15)) * 64 +
                                    ks * 32 + (lane >> 4) * 8];
#pragma unroll
      for (int nt = 0; nt < 2; ++nt)
        b[nt] = *(const bf16x8*)&Bs[(nt * 16 + (lane & 15)) * 64 +
                                    ks * 32 + (lane >> 4) * 8];
#pragma unroll
      for (int mt = 0; mt < 2; ++mt)
#pragma unroll
        for (int nt = 0; nt < 2; ++nt)
          acc[mt][nt] = __builtin_amdgcn_mfma_f32_16x16x32_bf16(
              a[mt], b[nt], acc[mt][nt], 0, 0, 0);
    }
  }
  // C/D layout: col = lane&15, row = (lane>>4)*4 + reg
  float* dst = axp + (size_t)blockIdx.y * M_TOT * R_;
#pragma unroll
  for (int mt = 0; mt < 2; ++mt)
#pragma unroll
    for (int nt = 0; nt < 2; ++nt)
#pragma unroll
      for (int r = 0; r < 4; ++r) {
        int m = m0 + wv * 32 + mt * 16 + (lane >> 4) * 4 + r;
        int n = nt * 16 + (lane & 15);
        dst[(size_t)m * R_ + n] = acc[mt][nt][r];
      }
}

// axb = bf16( 0.5 * sum_ks axp[ks] )
__global__ void ax_reduce(const float* __restrict__ axp,
                          bf16_t* __restrict__ axb, int n4) {
  int i = blockIdx.x * blockDim.x + threadIdx.x;
  if (i >= n4) return;
  f32x4 s = (f32x4){0.f, 0.f, 0.f, 0.f};
#pragma unroll
  for (int ks = 0; ks < KSPLIT; ++ks)
    s += ((const f32x4*)(axp + (size_t)ks * M_TOT * R_))[i];
  bf16x4 o = { (bf16_t)(0.5f * s[0]), (bf16_t)(0.5f * s[1]),
               (bf16_t)(0.5f * s[2]), (bf16_t)(0.5f * s[3]) };
  ((bf16x4*)axb)[i] = o;
}

// ------------------------------------- out = [Xb|axb] @ [Wb|Bb]^T + bias ----
// 128x128 tile, BK=32, 4 waves (2x2), each 64x64 (4x4 MFMA 16x16x32 tiles).
// Branch-free K-loop with pointer increments; LoRA K-step peeled.
__global__ __launch_bounds__(256) void main_gemm(
    const bf16_t* __restrict__ Xb, const bf16_t* __restrict__ Wb,
    const bf16_t* __restrict__ axb, const bf16_t* __restrict__ Bb,
    const float* __restrict__ bias, float* __restrict__ out) {
  __shared__ bf16_t As[128 * 32];
  __shared__ bf16_t Bs[128 * 32];
  const int tid = threadIdx.x, lane = tid & 63, wv = tid >> 6;
  const int wr = wv & 1, wc = wv >> 1;
  const int m0 = blockIdx.y * 128, n0 = blockIdx.x * 128;

  // staging: wave wv stages 16 rows (4 lanes/row, 16B each); two row-halves
  const int srow = wv * 16 + (lane >> 2);
  const int skk = (lane & 3) * 8;
  const bf16_t* pa0 = Xb + (size_t)(m0 + srow) * DIN + skk;
  const bf16_t* pa1 = pa0 + (size_t)64 * DIN;
  const bf16_t* pb0 = Wb + (size_t)(n0 + srow) * DIN + skk;
  const bf16_t* pb1 = pb0 + (size_t)64 * DIN;
  bf16_t* lA0 = As + wv * 512;
  bf16_t* lA1 = As + 2048 + wv * 512;
  bf16_t* lB0 = Bs + wv * 512;
  bf16_t* lB1 = Bs + 2048 + wv * 512;

  // LDS read offsets (loop-invariant)
  int offA[4], offB[4];
#pragma unroll
  for (int t = 0; t < 4; ++t) {
    offA[t] = (wr * 64 + t * 16 + (lane & 15)) * 32 + (lane >> 4) * 8;
    offB[t] = (wc * 64 + t * 16 + (lane & 15)) * 32 + (lane >> 4) * 8;
  }

  f32x4 acc[4][4];
#pragma unroll
  for (int i = 0; i < 4; ++i)
#pragma unroll
    for (int j = 0; j < 4; ++j) acc[i][j] = (f32x4){0.f, 0.f, 0.f, 0.f};

  for (int kt = 0; kt < 128; ++kt) {
    __syncthreads();
    async_cp16(pa0, lA0);
    async_cp16(pa1, lA1);
    async_cp16(pb0, lB0);
    async_cp16(pb1, lB1);
    pa0 += 32; pa1 += 32; pb0 += 32; pb1 += 32;
    __syncthreads();
    bf16x8 a[4], b[4];
#pragma unroll
    for (int t = 0; t < 4; ++t) {
      a[t] = *(const bf16x8*)&As[offA[t]];
      b[t] = *(const bf16x8*)&Bs[offB[t]];
    }
#pragma unroll
    for (int mt = 0; mt < 4; ++mt)
#pragma unroll
      for (int nt = 0; nt < 4; ++nt)
        acc[mt][nt] = __builtin_amdgcn_mfma_f32_16x16x32_bf16(
            a[mt], b[nt], acc[mt][nt], 0, 0, 0);
  }
  // peeled LoRA K-step (K rows of length R_=32)
  __syncthreads();
  async_cp16(axb + (size_t)(m0 + srow) * R_ + skk, lA0);
  async_cp16(axb + (size_t)(m0 + 64 + srow) * R_ + skk, lA1);
  async_cp16(Bb + (size_t)(n0 + srow) * R_ + skk, lB0);
  async_cp16(Bb + (size_t)(n0 + 64 + srow) * R_ + skk, lB1);
  __syncthreads();
  {
    bf16x8 a[4], b[4];
#pragma unroll
    for (int t = 0; t < 4; ++t) {
      a[t] = *(const bf16x8*)&As[offA[t]];
      b[t] = *(const bf16x8*)&Bs[offB[t]];
    }
#pragma unroll
    for (int mt = 0; mt < 4; ++mt)
#pragma unroll
      for (int nt = 0; nt < 4; ++nt)
        acc[mt][nt] = __builtin_amdgcn_mfma_f32_16x16x32_bf16(
            a[mt], b[nt], acc[mt][nt], 0, 0, 0);
  }
  // epilogue: +bias, fp32 store. C/D: col=lane&15, row=(lane>>4)*4+reg
#pragma unroll
  for (int nt = 0; nt < 4; ++nt) {
    int n = n0 + wc * 64 + nt * 16 + (lane & 15);
    float bv = bias[n];
#pragma unroll
    for (int mt = 0; mt < 4; ++mt) {
      int m = m0 + wr * 64 + mt * 16 + (lane >> 4) * 4;
#pragma unroll
      for (int r = 0; r < 4; ++r)
        out[(size_t)(m + r) * DOUT + n] = acc[mt][nt][r] + bv;
    }
  }
}

// ---------------------------------------------------------------------------
extern "C" void kernel_launch(void* const* d_in, const int* in_sizes, int n_in,
                              void* d_out, int out_size, void* d_ws, size_t ws_size,
                              hipStream_t stream) {
  const float* X      = (const float*)d_in[0];  // [8,2048,4096]
  const float* W      = (const float*)d_in[1];  // [4096,4096]
  const float* bias   = (const float*)d_in[2];  // [4096]
  const float* lora_A = (const float*)d_in[3];  // [5,4096,32]
  const float* lora_B = (const float*)d_in[4];  // [4096,32]
  const int*   lab    = (const int*)d_in[5];    // [8]
  float* out = (float*)d_out;

  // ws layout (bytes): Xb 128M | Wb 32M | At 1.25M | Bb 256K | axb 1M | axp 16M
  char* ws = (char*)d_ws;
  bf16_t* Xb  = (bf16_t*)(ws);
  bf16_t* Wb  = (bf16_t*)(ws + 134217728UL);
  bf16_t* At  = (bf16_t*)(ws + 167772160UL);
  bf16_t* Bb  = (bf16_t*)(ws + 169082880UL);
  bf16_t* axb = (bf16_t*)(ws + 169345024UL);
  float*  axp = (float*)(ws + 170393600UL);   // 16 MB, ends at ~187 MB

  cast_f32_to_bf16<<<65536, 256, 0, stream>>>(X, Xb, (M_TOT * DIN) / 4);
  cast_f32_to_bf16<<<16384, 256, 0, stream>>>(W, Wb, (DOUT * DIN) / 4);
  cast_f32_to_bf16<<<128, 256, 0, stream>>>(lora_B, Bb, (DOUT * R_) / 4);
  transpose_loraA<<<5 * (DIN / 64), 256, 0, stream>>>(lora_A, At);
  ax_partial<<<dim3(M_TOT / 128, KSPLIT), 256, 0, stream>>>(Xb, At, lab, axp);
  ax_reduce<<<(M_TOT * R_ / 4 + 255) / 256, 256, 0, stream>>>(
      axp, axb, M_TOT * R_ / 4);
  dim3 grid(DOUT / 128, M_TOT / 128);
  main_gemm<<<grid, 256, 0, stream>>>(Xb, Wb, axb, Bb, bias, out);
}